// Round 1
// baseline (289.312 us; speedup 1.0000x reference)
//
#include <hip/hip_runtime.h>
#include <hip/hip_bf16.h>
#include <float.h>

#define H 2048
#define E 64
#define TOPK 8
#define TT 8     // tokens per block (was 16; halves LDS -> 4 blocks/CU)
#define NT 512   // threads per block (8 waves)

typedef __attribute__((ext_vector_type(8))) short bf16x8;
typedef __attribute__((ext_vector_type(4))) float f32x4;
typedef __attribute__((ext_vector_type(4))) unsigned short us4;

__device__ __forceinline__ unsigned short f2bf(float f) {
  unsigned u = __float_as_uint(f);
  u += 0x7fffu + ((u >> 16) & 1u);   // RNE
  return (unsigned short)(u >> 16);
}
__device__ __forceinline__ float bf2f(unsigned short s) {
  return __uint_as_float(((unsigned)s) << 16);
}
__device__ __forceinline__ float wred_max(float v) {
#pragma unroll
  for (int o = 32; o > 0; o >>= 1) v = fmaxf(v, __shfl_xor(v, o));
  return v;
}
__device__ __forceinline__ float wred_sum(float v) {
#pragma unroll
  for (int o = 32; o > 0; o >>= 1) v += __shfl_xor(v, o);
  return v;
}

// Convert router_weight and expert_bias fp32 -> bf16 into workspace (L2-resident).
__global__ __launch_bounds__(256) void cvt_kernel(const float* __restrict__ W,
                                                  const float* __restrict__ eb,
                                                  unsigned short* __restrict__ Wb,
                                                  unsigned short* __restrict__ Bb) {
  int i = (blockIdx.x * 256 + threadIdx.x) * 4;
  const float* src;
  unsigned short* dst;
  int off;
  if (i < E * H) { src = W; dst = Wb; off = i; }
  else           { src = eb; dst = Bb; off = i - E * H; }
  float4 v = *(const float4*)(src + off);
  us4 r;
  r[0] = f2bf(v.x); r[1] = f2bf(v.y); r[2] = f2bf(v.z); r[3] = f2bf(v.w);
  *(us4*)(dst + off) = r;
}

template <bool USE_WS>
__global__ __launch_bounds__(NT, 8) void moe_kernel(
    const float* __restrict__ x, const float* __restrict__ W,
    const float* __restrict__ rb, const float* __restrict__ eb,
    const unsigned short* __restrict__ Wb, const unsigned short* __restrict__ Bb,
    float* __restrict__ out) {
  // LDS total ~37.6 KB -> 4 blocks/CU (was 71 KB -> 2 blocks/CU)
  __shared__ unsigned short xl[TT][H + 8];   // 32896 B; +8 pad = 4-bank shift/row
  __shared__ float lgp[2][TT][E + 1];        // 4160 B; split-K partial logits
  __shared__ float msw[TT];
  __shared__ float mw[TT][TOPK];
  __shared__ int   mi[TT][TOPK];             // element offsets e*H

  const int tid = threadIdx.x;
  const int t0  = blockIdx.x * TT;
  const int wv = tid >> 6, lane = tid & 63, quad = lane >> 4, m = lane & 15;

  // ---- Phase A: stage x tile into LDS as bf16; wave wv stages row wv ----
  {
    const float* row = x + (size_t)(t0 + wv) * H;
#pragma unroll
    for (int i = 0; i < 8; ++i) {
      const int c = (i * 64 + lane) * 4;
      float4 a = *(const float4*)(row + c);
      us4 ra;
      ra[0] = f2bf(a.x); ra[1] = f2bf(a.y); ra[2] = f2bf(a.z); ra[3] = f2bf(a.w);
      *(us4*)&xl[wv][c] = ra;
    }
  }
  __syncthreads();

  // ---- Phase B: logits[8 tok x 64 exp] via MFMA, split-K over all 8 waves.
  // wave wv: expert group (wv&3)*16, K-half (wv>>2). M rows 8..15 duplicate
  // tokens 0..7 (A row = lane&15 -> xl[(lane&15)&7]); their outputs discarded.
  {
    const int eg = wv & 3, kh = wv >> 2;
    const int e = eg * 16 + m;
    const int k0 = kh * (H / 2);
    f32x4 acc = {0.f, 0.f, 0.f, 0.f};
    const unsigned short* xp = &xl[m & 7][k0 + quad * 8];
    if (USE_WS) {
      const unsigned short* wp = Wb + (size_t)e * H + k0 + quad * 8;
#pragma unroll 8
      for (int it = 0; it < H / 64; ++it) {   // 32 iters
        bf16x8 av = *(const bf16x8*)(xp + it * 32);
        bf16x8 bv = *(const bf16x8*)(wp + it * 32);
        acc = __builtin_amdgcn_mfma_f32_16x16x32_bf16(av, bv, acc, 0, 0, 0);
      }
    } else {
      const float* wp = W + (size_t)e * H + k0 + quad * 8;
#pragma unroll 4
      for (int it = 0; it < H / 64; ++it) {
        bf16x8 av = *(const bf16x8*)(xp + it * 32);
        float4 p = *(const float4*)(wp + it * 32);
        float4 q = *(const float4*)(wp + it * 32 + 4);
        bf16x8 bv;
        bv[0] = (short)f2bf(p.x); bv[1] = (short)f2bf(p.y);
        bv[2] = (short)f2bf(p.z); bv[3] = (short)f2bf(p.w);
        bv[4] = (short)f2bf(q.x); bv[5] = (short)f2bf(q.y);
        bv[6] = (short)f2bf(q.z); bv[7] = (short)f2bf(q.w);
        acc = __builtin_amdgcn_mfma_f32_16x16x32_bf16(av, bv, acc, 0, 0, 0);
      }
    }
    // C/D layout: col = lane&15 (expert-in-group), row = quad*4+r (token)
#pragma unroll
    for (int r = 0; r < 4; ++r) {
      const int row = quad * 4 + r;
      if (row < TT) lgp[kh][row][eg * 16 + m] = acc[r];
    }
  }
  __syncthreads();

  // ---- Phase B': softmax + top-8. Wave wv handles token wv; lane = expert.
  {
    const int t = wv;
    float l = lgp[0][t][lane] + lgp[1][t][lane] + rb[lane];
    const float mx = wred_max(l);
    const float p = expf(l - mx);
    const float inv = 1.f / wred_sum(p);
    float sumw = 0.f;
    float lsel = l;
#pragma unroll
    for (int k = 0; k < TOPK; ++k) {
      const float mk = wred_max(lsel);
      const unsigned long long b = __ballot(lsel == mk);
      const int idx = __ffsll(b) - 1;          // tie -> lowest index (matches top_k)
      const float wk = expf(mk - mx) * inv;
      sumw += wk;
      if (lane == 0) { mw[t][k] = wk; mi[t][k] = idx * H; }
      if (lane == idx) lsel = -FLT_MAX;
    }
    if (lane == 0) msw[t] = sumw;
  }
  __syncthreads();

  // ---- Phase C: out[t][h] = x[t][h]*sum_w + sum_k w_k * bias[idx_k][h] ----
  // Thread group tg = tid>>8 handles 4 tokens; 16 B/lane loads everywhere.
  {
    const int tg = tid >> 8;
    const int c8 = (tid & 255) * 8;
    const unsigned short* bbase = Bb + c8;   // unused if !USE_WS
    const float* ebase = eb + c8;
#pragma unroll 1
    for (int tt = 0; tt < TT / 2; ++tt) {
      const int t = tg * (TT / 2) + tt;
      const float sw = msw[t];
      const float4 w0 = *(const float4*)&mw[t][0];
      const float4 w1 = *(const float4*)&mw[t][4];
      const int4  e0 = *(const int4*)&mi[t][0];
      const int4  e1 = *(const int4*)&mi[t][4];
      const float wks[8] = {w0.x, w0.y, w0.z, w0.w, w1.x, w1.y, w1.z, w1.w};
      const int   ofs[8] = {e0.x, e0.y, e0.z, e0.w, e1.x, e1.y, e1.z, e1.w};
      bf16x8 xv = *(const bf16x8*)&xl[t][c8];
      float o[8];
#pragma unroll
      for (int i = 0; i < 8; ++i) o[i] = bf2f((unsigned short)xv[i]) * sw;
#pragma unroll
      for (int k = 0; k < TOPK; ++k) {
        const float wk = wks[k];
        if (USE_WS) {
          bf16x8 bv = *(const bf16x8*)(bbase + ofs[k]);
#pragma unroll
          for (int i = 0; i < 8; ++i) o[i] += wk * bf2f((unsigned short)bv[i]);
        } else {
          const float* p = ebase + ofs[k];
          float4 p0 = *(const float4*)p;
          float4 p1 = *(const float4*)(p + 4);
          o[0] += wk * p0.x; o[1] += wk * p0.y; o[2] += wk * p0.z; o[3] += wk * p0.w;
          o[4] += wk * p1.x; o[5] += wk * p1.y; o[6] += wk * p1.z; o[7] += wk * p1.w;
        }
      }
      float* op = out + (size_t)(t0 + t) * H + c8;
      *(float4*)op       = make_float4(o[0], o[1], o[2], o[3]);
      *(float4*)(op + 4) = make_float4(o[4], o[5], o[6], o[7]);
    }
  }
}

extern "C" void kernel_launch(void* const* d_in, const int* in_sizes, int n_in,
                              void* d_out, int out_size, void* d_ws, size_t ws_size,
                              hipStream_t stream) {
  const float* x  = (const float*)d_in[0];
  const float* W  = (const float*)d_in[1];
  const float* rb = (const float*)d_in[2];
  const float* eb = (const float*)d_in[3];
  float* out = (float*)d_out;

  const int T = in_sizes[0] / H;     // 16384
  const int grid = T / TT;           // 2048

  const size_t need = (size_t)2 * E * H * sizeof(unsigned short);  // 512 KB
  if (ws_size >= need) {
    unsigned short* Wb = (unsigned short*)d_ws;
    unsigned short* Bb = Wb + E * H;
    cvt_kernel<<<(2 * E * H) / (256 * 4), 256, 0, stream>>>(W, eb, Wb, Bb);
    moe_kernel<true><<<grid, NT, 0, stream>>>(x, W, rb, eb, Wb, Bb, out);
  } else {
    moe_kernel<false><<<grid, NT, 0, stream>>>(x, W, rb, eb, nullptr, nullptr, out);
  }
}